// Round 1
// baseline (348.660 us; speedup 1.0000x reference)
//
#include <hip/hip_runtime.h>

// Problem constants
#define B_ 4
#define S_ 2048
#define H_ 16
#define D_ 64
#define E_ 1024
#define M_ 8192   // B_*S_

typedef __attribute__((ext_vector_type(8))) __bf16 bf16x8;
typedef __attribute__((ext_vector_type(4))) __bf16 bf16x4;
typedef __attribute__((ext_vector_type(4))) float f32x4;

// async global->LDS, 16B per lane; LDS base must be wave-uniform
__device__ __forceinline__ void gload_lds16(const void* g, void* l) {
  __builtin_amdgcn_global_load_lds(
      (const __attribute__((address_space(1))) unsigned int*)g,
      (__attribute__((address_space(3))) unsigned int*)l, 16, 0, 0);
}

// ---------------- fp32 -> bf16 convert (vectorized, G13) ----------------
__global__ void cvt_f32_bf16(const float* __restrict__ in, __bf16* __restrict__ out) {
  const int i = blockIdx.x * blockDim.x + threadIdx.x;  // exactly n/4 threads
  const float4 v = ((const float4*)in)[i];
  bf16x4 o;
  o.x = (__bf16)v.x; o.y = (__bf16)v.y; o.z = (__bf16)v.z; o.w = (__bf16)v.w;
  ((bf16x4*)out)[i] = o;
}

// ---------------- weight packing into B^T layout [n][k] bf16 ----------------
// Bq[n][k] = wq[n/64][k][n%64]   (n = h*64+e, k = d)
__global__ void pack_head_w(const float* __restrict__ w, __bf16* __restrict__ out) {
  const int idx = blockIdx.x * 256 + threadIdx.x;  // 1024*1024 total
  const int n = idx >> 10, k = idx & 1023;
  out[idx] = (__bf16)w[((size_t)(n >> 6) << 16) + (k << 6) + (n & 63)];
}
// Bo[n][k] = wo[k][n]
__global__ void pack_wo(const float* __restrict__ w, __bf16* __restrict__ out) {
  const int idx = blockIdx.x * 256 + threadIdx.x;
  const int n = idx >> 10, k = idx & 1023;
  out[idx] = (__bf16)w[((size_t)k << 10) + n];
}

// ---------------- bf16 MFMA GEMM: C[M,N] = A[M,K] * Bt[N,K]^T + bias -------
// 128x128 tile, BK=64, 256 threads (4 waves, 2x2), global_load_lds w16,
// XOR chunk-swizzle (rule 21: linear LDS dest + inverse-swizzled source +
// swizzled ds_read) -> <=2-way LDS bank conflicts.
// MODE 0: scatter bf16 to [B,H,S,D], bias[gn]
// MODE 1: scatter bf16 to [B,H,D,S] (A is weights, Bt is activations), bias[gm]
// MODE 2: fp32 C[gm*1024+gn] = acc + bias[gn]
template <int MODE>
__global__ __launch_bounds__(256) void gemm_bt(const __bf16* __restrict__ A,
                                               const __bf16* __restrict__ Bt,
                                               const float* __restrict__ bias,
                                               void* __restrict__ Cout) {
  constexpr int K = 1024;
  __shared__ __bf16 As[128 * 64];
  __shared__ __bf16 Bs[128 * 64];
  const int t = threadIdx.x;
  const int w = t >> 6, l = t & 63;
  const int m0 = blockIdx.x * 128, n0 = blockIdx.y * 128;
  f32x4 acc[4][4] = {};

  for (int kt = 0; kt < K / 64; ++kt) {
    const int kb = kt * 64;
#pragma unroll
    for (int j = 0; j < 4; ++j) {
      const int ci = (j * 4 + w) * 64 + l;     // 16B-chunk index in tile
      const int row = ci >> 3;                 // 8 chunks per 128B row
      const int c = (ci & 7) ^ (row & 7);      // inverse-swizzled source chunk
      gload_lds16(A + (size_t)(m0 + row) * K + kb + c * 8, As + (j * 4 + w) * 512);
      gload_lds16(Bt + (size_t)(n0 + row) * K + kb + c * 8, Bs + (j * 4 + w) * 512);
    }
    __syncthreads();
#pragma unroll
    for (int kk = 0; kk < 64; kk += 32) {
      bf16x8 af[4], bfr[4];
#pragma unroll
      for (int f = 0; f < 4; ++f) {
        const int ra = (w >> 1) * 64 + f * 16 + (l & 15);
        const int ca = ((kk >> 3) + (l >> 4)) ^ (ra & 7);
        af[f] = *(const bf16x8*)(As + ra * 64 + ca * 8);
        const int rb = (w & 1) * 64 + f * 16 + (l & 15);
        const int cb = ((kk >> 3) + (l >> 4)) ^ (rb & 7);
        bfr[f] = *(const bf16x8*)(Bs + rb * 64 + cb * 8);
      }
#pragma unroll
      for (int mf = 0; mf < 4; ++mf)
#pragma unroll
        for (int nf = 0; nf < 4; ++nf)
          acc[mf][nf] = __builtin_amdgcn_mfma_f32_16x16x32_bf16(af[mf], bfr[nf],
                                                                acc[mf][nf], 0, 0, 0);
    }
    __syncthreads();
  }

  // epilogue: C/D layout col=lane&15, row=(lane>>4)*4+reg
#pragma unroll
  for (int mf = 0; mf < 4; ++mf) {
#pragma unroll
    for (int nf = 0; nf < 4; ++nf) {
#pragma unroll
      for (int r = 0; r < 4; ++r) {
        const int gm = m0 + (w >> 1) * 64 + mf * 16 + (l >> 4) * 4 + r;
        const int gn = n0 + (w & 1) * 64 + nf * 16 + (l & 15);
        const float val = acc[mf][nf][r] + ((MODE == 1) ? bias[gm] : bias[gn]);
        if constexpr (MODE == 0) {
          ((__bf16*)Cout)[(((size_t)(gm >> 11) * H_ + (gn >> 6)) * S_ + (gm & 2047)) * D_ + (gn & 63)] =
              (__bf16)val;
        } else if constexpr (MODE == 1) {
          ((__bf16*)Cout)[(((size_t)(gn >> 11) * H_ + (gm >> 6)) * D_ + (gm & 63)) * S_ + (gn & 2047)] =
              (__bf16)val;
        } else {
          ((float*)Cout)[(size_t)gm * 1024 + gn] = val;
        }
      }
    }
  }
}

// ---------------- fused causal flash attention ----------------
// grid (32 qtiles, 64 bh); 256 threads = 4 waves, wave w owns q rows qt*64+w*16..+15
// qh,kh: [B,H,S,64] bf16 ; vT: [B,H,64,S] bf16 ; concat out: [B*S,1024] bf16
__global__ __launch_bounds__(256) void attn_fused(const __bf16* __restrict__ qh,
                                                  const __bf16* __restrict__ kh,
                                                  const __bf16* __restrict__ vT,
                                                  __bf16* __restrict__ concat,
                                                  const int* __restrict__ use_mask_p) {
  __shared__ __bf16 Ks[64 * 64];
  __shared__ __bf16 Vs[64 * 64];
  __shared__ __bf16 Pl[4][16 * 72];  // per-wave, stride 72 (pad: 2-way max)
  const int t = threadIdx.x, w = t >> 6, l = t & 63;
  const int qt = blockIdx.x, bh = blockIdx.y;
  const int usemask = *use_mask_p;
  const __bf16* Qb = qh + (size_t)bh * S_ * D_;
  const __bf16* Kb = kh + (size_t)bh * S_ * D_;
  const __bf16* Vb = vT + (size_t)bh * D_ * S_;
  const int qrow0 = qt * 64 + w * 16;

  // Q fragments (A-layout: row=l&15, k contiguous 8 at (l>>4)*8), loop-invariant
  bf16x8 qf[2];
#pragma unroll
  for (int kf = 0; kf < 2; ++kf)
    qf[kf] = *(const bf16x8*)(Qb + (size_t)(qrow0 + (l & 15)) * D_ + kf * 32 + (l >> 4) * 8);

  float mrow[4] = {-3e38f, -3e38f, -3e38f, -3e38f};
  float lsum[4] = {0.f, 0.f, 0.f, 0.f};
  f32x4 o[4] = {};
  const int ktend = usemask ? qt : (S_ / 64 - 1);

  for (int kt = 0; kt <= ktend; ++kt) {
    // stage K tile [64 krow][64 e] and V^T tile [64 e][64 k], swizzled
#pragma unroll
    for (int j = 0; j < 2; ++j) {
      const int ci = (j * 4 + w) * 64 + l;
      const int row = ci >> 3;
      const int c = (ci & 7) ^ (row & 7);
      gload_lds16(Kb + (size_t)(kt * 64 + row) * D_ + c * 8, Ks + (j * 4 + w) * 512);
      gload_lds16(Vb + (size_t)row * S_ + kt * 64 + c * 8, Vs + (j * 4 + w) * 512);
    }
    __syncthreads();

    // S = Q K^T  (k-dim = e = 64 -> 2 MFMA steps; 4 n-frags over 64 k-rows)
    f32x4 s[4] = {};
#pragma unroll
    for (int kf = 0; kf < 2; ++kf) {
      bf16x8 kfrag[4];
#pragma unroll
      for (int nf = 0; nf < 4; ++nf) {
        const int row = nf * 16 + (l & 15);
        const int c = (kf * 4 + (l >> 4)) ^ (row & 7);
        kfrag[nf] = *(const bf16x8*)(Ks + row * 64 + c * 8);
      }
#pragma unroll
      for (int nf = 0; nf < 4; ++nf)
        s[nf] = __builtin_amdgcn_mfma_f32_16x16x32_bf16(qf[kf], kfrag[nf], s[nf], 0, 0, 0);
    }
#pragma unroll
    for (int nf = 0; nf < 4; ++nf) s[nf] *= 0.125f;  // 1/sqrt(64)

    if (usemask && kt == qt) {  // diagonal tile: in-tile causal mask
#pragma unroll
      for (int nf = 0; nf < 4; ++nf) {
        const int col = kt * 64 + nf * 16 + (l & 15);
#pragma unroll
        for (int r = 0; r < 4; ++r) {
          const int rq = qrow0 + (l >> 4) * 4 + r;
          if (col > rq) s[nf][r] = -1e30f;
        }
      }
    }

    // online softmax; row stats live in the 16-lane column group
    float pm[4], al[4];
#pragma unroll
    for (int r = 0; r < 4; ++r)
      pm[r] = fmaxf(fmaxf(s[0][r], s[1][r]), fmaxf(s[2][r], s[3][r]));
#pragma unroll
    for (int off = 1; off < 16; off <<= 1)
#pragma unroll
      for (int r = 0; r < 4; ++r) pm[r] = fmaxf(pm[r], __shfl_xor(pm[r], off));
#pragma unroll
    for (int r = 0; r < 4; ++r) {
      const float mn = fmaxf(mrow[r], pm[r]);
      al[r] = __builtin_amdgcn_exp2f((mrow[r] - mn) * 1.4426950408889634f);
      mrow[r] = mn;
    }
    f32x4 p[4];
    float rs[4] = {0.f, 0.f, 0.f, 0.f};
#pragma unroll
    for (int nf = 0; nf < 4; ++nf)
#pragma unroll
      for (int r = 0; r < 4; ++r) {
        p[nf][r] = __builtin_amdgcn_exp2f((s[nf][r] - mrow[r]) * 1.4426950408889634f);
        rs[r] += p[nf][r];
      }
#pragma unroll
    for (int off = 1; off < 16; off <<= 1)
#pragma unroll
      for (int r = 0; r < 4; ++r) rs[r] += __shfl_xor(rs[r], off);
#pragma unroll
    for (int r = 0; r < 4; ++r) lsum[r] = lsum[r] * al[r] + rs[r];
#pragma unroll
    for (int nf = 0; nf < 4; ++nf)
#pragma unroll
      for (int r = 0; r < 4; ++r) o[nf][r] *= al[r];

    // P: C-layout -> A-layout via wave-private padded LDS (no barrier needed)
    __bf16* Pw = &Pl[w][0];
#pragma unroll
    for (int nf = 0; nf < 4; ++nf)
#pragma unroll
      for (int r = 0; r < 4; ++r)
        Pw[((l >> 4) * 4 + r) * 72 + nf * 16 + (l & 15)] = (__bf16)p[nf][r];

    // O += P V   (k-dim = 64 kv rows -> 2 MFMA steps; 4 n-frags over e)
#pragma unroll
    for (int kk = 0; kk < 2; ++kk) {
      const bf16x8 pa = *(const bf16x8*)(Pw + (l & 15) * 72 + kk * 32 + (l >> 4) * 8);
      bf16x8 vf[4];
#pragma unroll
      for (int nf = 0; nf < 4; ++nf) {
        const int row = nf * 16 + (l & 15);
        const int c = (kk * 4 + (l >> 4)) ^ (row & 7);
        vf[nf] = *(const bf16x8*)(Vs + row * 64 + c * 8);
      }
#pragma unroll
      for (int nf = 0; nf < 4; ++nf)
        o[nf] = __builtin_amdgcn_mfma_f32_16x16x32_bf16(pa, vf[nf], o[nf], 0, 0, 0);
    }
    __syncthreads();
  }

  // epilogue: concat[b*S+s][h*64+e] = o / lsum
  const int b = bh >> 4, hh = bh & 15;
#pragma unroll
  for (int r = 0; r < 4; ++r) {
    const float inv = 1.0f / lsum[r];
    const int srow = qrow0 + (l >> 4) * 4 + r;
#pragma unroll
    for (int nf = 0; nf < 4; ++nf)
      concat[((size_t)(b * S_ + srow)) * E_ + hh * 64 + nf * 16 + (l & 15)] =
          (__bf16)(o[nf][r] * inv);
  }
}

// ---------------- launch ----------------
extern "C" void kernel_launch(void* const* d_in, const int* in_sizes, int n_in,
                              void* d_out, int out_size, void* d_ws, size_t ws_size,
                              hipStream_t stream) {
  const float* q = (const float*)d_in[0];
  const float* k = (const float*)d_in[1];
  const float* v = (const float*)d_in[2];
  const float* wq = (const float*)d_in[3];
  const float* bq = (const float*)d_in[4];
  const float* wk = (const float*)d_in[5];
  const float* bk = (const float*)d_in[6];
  const float* wv = (const float*)d_in[7];
  const float* bv = (const float*)d_in[8];
  const float* wo = (const float*)d_in[9];
  const float* bo = (const float*)d_in[10];
  const int* use_mask = (const int*)d_in[11];
  (void)in_sizes; (void)n_in; (void)out_size; (void)ws_size;

  char* ws = (char*)d_ws;
  __bf16* Aq = (__bf16*)ws;                       // [8192,1024] bf16
  __bf16* Ak = Aq + (size_t)M_ * E_;
  __bf16* Av = Ak + (size_t)M_ * E_;
  __bf16* Bq = Av + (size_t)M_ * E_;              // packed weights [1024,1024]
  __bf16* Bk = Bq + (size_t)E_ * E_;
  __bf16* Bv = Bk + (size_t)E_ * E_;
  __bf16* Bo = Bv + (size_t)E_ * E_;
  __bf16* qhb = Bo + (size_t)E_ * E_;             // [B,H,S,64]
  __bf16* khb = qhb + (size_t)M_ * E_ / 16 * 16;  // same size as qhb
  __bf16* vTb = khb + (size_t)M_ * E_;            // wait: qh/kh are M_*D_*H_ = M_*1024
  // NOTE: qh/kh/vT are each B*H*S*D = 8192*1024 elements (== M_*E_... no, M_*D_*H_/?).
  // B*H*S*D = 4*16*2048*64 = 8,388,608 = M_*E_/1? (8192*1024 = 8,388,608). Yes equal.
  __bf16* concat = Aq;  // reuse Aq region after projections are consumed

  // fix pointer chain cleanly (qh/kh/vT each 8,388,608 elements):
  qhb = Bo + (size_t)E_ * E_;
  khb = qhb + (size_t)8388608;
  vTb = khb + (size_t)8388608;

  // 1) converts
  cvt_f32_bf16<<<8192, 256, 0, stream>>>(q, Aq);
  cvt_f32_bf16<<<8192, 256, 0, stream>>>(k, Ak);
  cvt_f32_bf16<<<8192, 256, 0, stream>>>(v, Av);
  // 2) weight packs
  pack_head_w<<<4096, 256, 0, stream>>>(wq, Bq);
  pack_head_w<<<4096, 256, 0, stream>>>(wk, Bk);
  pack_head_w<<<4096, 256, 0, stream>>>(wv, Bv);
  pack_wo<<<4096, 256, 0, stream>>>(wo, Bo);
  // 3) projections
  gemm_bt<0><<<dim3(64, 8), 256, 0, stream>>>(Aq, Bq, bq, qhb);
  gemm_bt<0><<<dim3(64, 8), 256, 0, stream>>>(Ak, Bk, bk, khb);
  // v projection computed transposed: C[e_flat, s_flat] = Bv * Av^T -> [B,H,D,S]
  gemm_bt<1><<<dim3(8, 64), 256, 0, stream>>>(Bv, Av, bv, vTb);
  // 4) fused causal attention -> concat bf16 [8192,1024]
  attn_fused<<<dim3(32, 64), 256, 0, stream>>>(qhb, khb, vTb, concat, use_mask);
  // 5) output projection -> fp32 out
  gemm_bt<2><<<dim3(64, 8), 256, 0, stream>>>(concat, Bo, bo, d_out);
}

// Round 2
// 238.245 us; speedup vs baseline: 1.4635x; 1.4635x over previous
//
#include <hip/hip_runtime.h>

// Problem constants
#define B_ 4
#define S_ 2048
#define H_ 16
#define D_ 64
#define E_ 1024
#define M_ 8192   // B_*S_

typedef __attribute__((ext_vector_type(8))) __bf16 bf16x8;
typedef __attribute__((ext_vector_type(4))) __bf16 bf16x4;
typedef __attribute__((ext_vector_type(4))) float f32x4;

// async global->LDS, 16B per lane; LDS base must be wave-uniform
__device__ __forceinline__ void gload_lds16(const void* g, void* l) {
  __builtin_amdgcn_global_load_lds(
      (const __attribute__((address_space(1))) unsigned int*)g,
      (__attribute__((address_space(3))) unsigned int*)l, 16, 0, 0);
}

// ---------------- fp32 -> bf16 convert (vectorized, G13) ----------------
__global__ void cvt_f32_bf16(const float* __restrict__ in, __bf16* __restrict__ out) {
  const int i = blockIdx.x * blockDim.x + threadIdx.x;  // exactly n/4 threads
  const float4 v = ((const float4*)in)[i];
  bf16x4 o;
  o.x = (__bf16)v.x; o.y = (__bf16)v.y; o.z = (__bf16)v.z; o.w = (__bf16)v.w;
  ((bf16x4*)out)[i] = o;
}

// ---------------- weight packing into B^T layout [n][k] bf16 ----------------
// Bq[n][k] = wq[n/64][k][n%64]   (n = h*64+e, k = d)
__global__ void pack_head_w(const float* __restrict__ w, __bf16* __restrict__ out) {
  const int idx = blockIdx.x * 256 + threadIdx.x;  // 1024*1024 total
  const int n = idx >> 10, k = idx & 1023;
  out[idx] = (__bf16)w[((size_t)(n >> 6) << 16) + (k << 6) + (n & 63)];
}
// Bo[n][k] = wo[k][n]
__global__ void pack_wo(const float* __restrict__ w, __bf16* __restrict__ out) {
  const int idx = blockIdx.x * 256 + threadIdx.x;
  const int n = idx >> 10, k = idx & 1023;
  out[idx] = (__bf16)w[((size_t)k << 10) + n];
}

// ---------------- bf16 MFMA GEMM: C[M,N] = A[M,K] * Bt[N,K]^T + bias -------
// 128x128 tile, BK=64, 256 threads (4 waves, 2x2), global_load_lds w16,
// XOR chunk-swizzle (rule 21) -> <=2-way LDS bank conflicts.
template <int MODE>
__global__ __launch_bounds__(256) void gemm_bt(const __bf16* __restrict__ A,
                                               const __bf16* __restrict__ Bt,
                                               const float* __restrict__ bias,
                                               void* __restrict__ Cout) {
  constexpr int K = 1024;
  __shared__ __bf16 As[128 * 64];
  __shared__ __bf16 Bs[128 * 64];
  const int t = threadIdx.x;
  const int w = t >> 6, l = t & 63;
  const int m0 = blockIdx.x * 128, n0 = blockIdx.y * 128;
  f32x4 acc[4][4] = {};

  for (int kt = 0; kt < K / 64; ++kt) {
    const int kb = kt * 64;
#pragma unroll
    for (int j = 0; j < 4; ++j) {
      const int ci = (j * 4 + w) * 64 + l;     // 16B-chunk index in tile
      const int row = ci >> 3;                 // 8 chunks per 128B row
      const int c = (ci & 7) ^ (row & 7);      // inverse-swizzled source chunk
      gload_lds16(A + (size_t)(m0 + row) * K + kb + c * 8, As + (j * 4 + w) * 512);
      gload_lds16(Bt + (size_t)(n0 + row) * K + kb + c * 8, Bs + (j * 4 + w) * 512);
    }
    __syncthreads();
#pragma unroll
    for (int kk = 0; kk < 64; kk += 32) {
      bf16x8 af[4], bfr[4];
#pragma unroll
      for (int f = 0; f < 4; ++f) {
        const int ra = (w >> 1) * 64 + f * 16 + (l & 15);
        const int ca = ((kk >> 3) + (l >> 4)) ^ (ra & 7);
        af[f] = *(const bf16x8*)(As + ra * 64 + ca * 8);
        const int rb = (w & 1) * 64 + f * 16 + (l & 15);
        const int cb = ((kk >> 3) + (l >> 4)) ^ (rb & 7);
        bfr[f] = *(const bf16x8*)(Bs + rb * 64 + cb * 8);
      }
#pragma unroll
      for (int mf = 0; mf < 4; ++mf)
#pragma unroll
        for (int nf = 0; nf < 4; ++nf)
          acc[mf][nf] = __builtin_amdgcn_mfma_f32_16x16x32_bf16(af[mf], bfr[nf],
                                                                acc[mf][nf], 0, 0, 0);
    }
    __syncthreads();
  }

#pragma unroll
  for (int mf = 0; mf < 4; ++mf) {
#pragma unroll
    for (int nf = 0; nf < 4; ++nf) {
#pragma unroll
      for (int r = 0; r < 4; ++r) {
        const int gm = m0 + (w >> 1) * 64 + mf * 16 + (l >> 4) * 4 + r;
        const int gn = n0 + (w & 1) * 64 + nf * 16 + (l & 15);
        const float val = acc[mf][nf][r] + ((MODE == 1) ? bias[gm] : bias[gn]);
        if constexpr (MODE == 0) {
          ((__bf16*)Cout)[(((size_t)(gm >> 11) * H_ + (gn >> 6)) * S_ + (gm & 2047)) * D_ + (gn & 63)] =
              (__bf16)val;
        } else if constexpr (MODE == 1) {
          ((__bf16*)Cout)[(((size_t)(gn >> 11) * H_ + (gm >> 6)) * D_ + (gm & 63)) * S_ + (gn & 2047)] =
              (__bf16)val;
        } else {
          ((float*)Cout)[(size_t)gm * 1024 + gn] = val;
        }
      }
    }
  }
}

// ---------------- fused causal flash attention (v2) ----------------
// grid (8 q-tile-pairs, 64 bh); 512 threads = 8 waves; Q-tile = 128 rows
// (wave w owns rows qt*128 + w*16 .. +15). KV tile 64, double-buffered LDS,
// 2-phase pipeline (stage kt+1 || compute kt, one raw barrier per iter).
// Causal pairing: block handles q-tiles (p, 15-p) -> every block = 34 iters.
__global__ __launch_bounds__(512) void attn_fused(const __bf16* __restrict__ qh,
                                                  const __bf16* __restrict__ kh,
                                                  const __bf16* __restrict__ vT,
                                                  __bf16* __restrict__ concat,
                                                  const int* __restrict__ use_mask_p) {
  __shared__ __bf16 Ks[2][64 * 64];
  __shared__ __bf16 Vs[2][64 * 64];
  __shared__ __bf16 Pl[8][16 * 72];  // per-wave, stride 72 (2-way max)
  const int t = threadIdx.x, w = t >> 6, l = t & 63;
  const int pair = blockIdx.x, bh = blockIdx.y;
  const int usemask = *use_mask_p;
  const __bf16* Qb = qh + (size_t)bh * S_ * D_;
  const __bf16* Kb = kh + (size_t)bh * S_ * D_;
  const __bf16* Vb = vT + (size_t)bh * D_ * S_;
  const int b = bh >> 4, hh = bh & 15;
  constexpr float LOG2E = 1.4426950408889634f;

  // staging geometry: 512 threads, one 16B chunk each for K and V
  const int srow = t >> 3;               // tile row 0..63
  const int sc = (t & 7) ^ (srow & 7);   // inverse-swizzled source chunk

  bf16x8 ones;
#pragma unroll
  for (int i = 0; i < 8; ++i) ones[i] = (__bf16)1.0f;

  __bf16* Pw = &Pl[w][0];
  int cur = 0;

  for (int half = 0; half < 2; ++half) {
    const int qt = half ? (15 - pair) : pair;
    const int qrow0 = qt * 128 + w * 16;
    const int ktend = usemask ? (2 * qt + 1) : (S_ / 64 - 1);

    // Q fragments (A-layout), loop-invariant for this q-tile
    bf16x8 qf[2];
#pragma unroll
    for (int kf = 0; kf < 2; ++kf)
      qf[kf] = *(const bf16x8*)(Qb + (size_t)(qrow0 + (l & 15)) * D_ + kf * 32 + (l >> 4) * 8);

    float mrow[4] = {-3e38f, -3e38f, -3e38f, -3e38f};
    f32x4 ls = {};      // row-sum accumulator (all 16 cols identical)
    f32x4 o[4] = {};

    // prologue: stage tile 0
    gload_lds16(Kb + (size_t)(0 * 64 + srow) * D_ + sc * 8, &Ks[cur][w * 512]);
    gload_lds16(Vb + (size_t)srow * S_ + 0 * 64 + sc * 8, &Vs[cur][w * 512]);
    __builtin_amdgcn_sched_barrier(0);
    asm volatile("s_waitcnt vmcnt(0)" ::: "memory");
    __builtin_amdgcn_s_barrier();
    __builtin_amdgcn_sched_barrier(0);

    for (int kt = 0; kt <= ktend; ++kt) {
      // issue next-tile stage (overlaps with this tile's compute)
      if (kt < ktend) {
        const int nxt = cur ^ 1;
        gload_lds16(Kb + (size_t)((kt + 1) * 64 + srow) * D_ + sc * 8, &Ks[nxt][w * 512]);
        gload_lds16(Vb + (size_t)srow * S_ + (kt + 1) * 64 + sc * 8, &Vs[nxt][w * 512]);
      }

      // ---- S = Q K^T ----
      f32x4 s[4] = {};
      __builtin_amdgcn_s_setprio(1);
#pragma unroll
      for (int kf = 0; kf < 2; ++kf) {
        bf16x8 kfrag[4];
#pragma unroll
        for (int nf = 0; nf < 4; ++nf) {
          const int row = nf * 16 + (l & 15);
          const int c = (kf * 4 + (l >> 4)) ^ (row & 7);
          kfrag[nf] = *(const bf16x8*)(&Ks[cur][row * 64 + c * 8]);
        }
#pragma unroll
        for (int nf = 0; nf < 4; ++nf)
          s[nf] = __builtin_amdgcn_mfma_f32_16x16x32_bf16(qf[kf], kfrag[nf], s[nf], 0, 0, 0);
      }
      __builtin_amdgcn_s_setprio(0);
#pragma unroll
      for (int nf = 0; nf < 4; ++nf) s[nf] *= 0.125f;  // 1/sqrt(64)

      if (usemask && kt * 64 + 63 > qrow0) {  // (partially) masked tile
#pragma unroll
        for (int nf = 0; nf < 4; ++nf) {
          const int col = kt * 64 + nf * 16 + (l & 15);
#pragma unroll
          for (int r = 0; r < 4; ++r) {
            const int rq = qrow0 + (l >> 4) * 4 + r;
            if (col > rq) s[nf][r] = -1e30f;
          }
        }
      }

      // ---- online softmax (max only; sum via ones-MFMA) ----
      float pm[4];
#pragma unroll
      for (int r = 0; r < 4; ++r)
        pm[r] = fmaxf(fmaxf(s[0][r], s[1][r]), fmaxf(s[2][r], s[3][r]));
#pragma unroll
      for (int off = 1; off < 16; off <<= 1)
#pragma unroll
        for (int r = 0; r < 4; ++r) pm[r] = fmaxf(pm[r], __shfl_xor(pm[r], off));

      // defer-max (T13): skip rescale when max growth <= 8 across the wave
      const int skip = __all((pm[0] - mrow[0] <= 8.0f) && (pm[1] - mrow[1] <= 8.0f) &&
                             (pm[2] - mrow[2] <= 8.0f) && (pm[3] - mrow[3] <= 8.0f));
      if (!skip) {
        float al[4];
#pragma unroll
        for (int r = 0; r < 4; ++r) {
          const float mn = fmaxf(mrow[r], pm[r]);
          al[r] = __builtin_amdgcn_exp2f((mrow[r] - mn) * LOG2E);
          mrow[r] = mn;
          ls[r] *= al[r];
        }
#pragma unroll
        for (int nf = 0; nf < 4; ++nf)
#pragma unroll
          for (int r = 0; r < 4; ++r) o[nf][r] *= al[r];
      }

      // P = exp(s - m); write to per-wave LDS (C-layout -> A-layout transpose)
#pragma unroll
      for (int nf = 0; nf < 4; ++nf)
#pragma unroll
        for (int r = 0; r < 4; ++r)
          Pw[((l >> 4) * 4 + r) * 72 + nf * 16 + (l & 15)] =
              (__bf16)__builtin_amdgcn_exp2f((s[nf][r] - mrow[r]) * LOG2E);

      // ---- O += P V ; ls += P·1 ----
      __builtin_amdgcn_s_setprio(1);
#pragma unroll
      for (int kk = 0; kk < 2; ++kk) {
        const bf16x8 pa = *(const bf16x8*)(Pw + (l & 15) * 72 + kk * 32 + (l >> 4) * 8);
        bf16x8 vf[4];
#pragma unroll
        for (int nf = 0; nf < 4; ++nf) {
          const int row = nf * 16 + (l & 15);
          const int c = (kk * 4 + (l >> 4)) ^ (row & 7);
          vf[nf] = *(const bf16x8*)(&Vs[cur][row * 64 + c * 8]);
        }
#pragma unroll
        for (int nf = 0; nf < 4; ++nf)
          o[nf] = __builtin_amdgcn_mfma_f32_16x16x32_bf16(pa, vf[nf], o[nf], 0, 0, 0);
        ls = __builtin_amdgcn_mfma_f32_16x16x32_bf16(pa, ones, ls, 0, 0, 0);
      }
      __builtin_amdgcn_s_setprio(0);

      // end-of-iteration: next tile's stage must be complete for everyone
      __builtin_amdgcn_sched_barrier(0);
      asm volatile("s_waitcnt vmcnt(0)" ::: "memory");
      __builtin_amdgcn_s_barrier();
      __builtin_amdgcn_sched_barrier(0);
      cur ^= 1;
    }

    // epilogue: concat[b*S+s][h*64+e] = o / ls
#pragma unroll
    for (int r = 0; r < 4; ++r) {
      const float inv = 1.0f / ls[r];
      const int qr = qrow0 + (l >> 4) * 4 + r;
#pragma unroll
      for (int nf = 0; nf < 4; ++nf)
        concat[((size_t)(b * S_ + qr)) * E_ + hh * 64 + nf * 16 + (l & 15)] =
            (__bf16)(o[nf][r] * inv);
    }
  }
}

// ---------------- launch ----------------
extern "C" void kernel_launch(void* const* d_in, const int* in_sizes, int n_in,
                              void* d_out, int out_size, void* d_ws, size_t ws_size,
                              hipStream_t stream) {
  const float* q = (const float*)d_in[0];
  const float* k = (const float*)d_in[1];
  const float* v = (const float*)d_in[2];
  const float* wq = (const float*)d_in[3];
  const float* bq = (const float*)d_in[4];
  const float* wk = (const float*)d_in[5];
  const float* bk = (const float*)d_in[6];
  const float* wv = (const float*)d_in[7];
  const float* bv = (const float*)d_in[8];
  const float* wo = (const float*)d_in[9];
  const float* bo = (const float*)d_in[10];
  const int* use_mask = (const int*)d_in[11];
  (void)in_sizes; (void)n_in; (void)out_size; (void)ws_size;

  char* ws = (char*)d_ws;
  __bf16* Aq = (__bf16*)ws;                       // [8192,1024] bf16
  __bf16* Ak = Aq + (size_t)M_ * E_;
  __bf16* Av = Ak + (size_t)M_ * E_;
  __bf16* Bq = Av + (size_t)M_ * E_;              // packed weights [1024,1024]
  __bf16* Bk = Bq + (size_t)E_ * E_;
  __bf16* Bv = Bk + (size_t)E_ * E_;
  __bf16* Bo = Bv + (size_t)E_ * E_;
  __bf16* qhb = Bo + (size_t)E_ * E_;             // [B,H,S,64]
  __bf16* khb = qhb + (size_t)8388608;
  __bf16* vTb = khb + (size_t)8388608;            // [B,H,64,S]
  __bf16* concat = Aq;  // reuse Aq region after projections are consumed

  // 1) converts
  cvt_f32_bf16<<<8192, 256, 0, stream>>>(q, Aq);
  cvt_f32_bf16<<<8192, 256, 0, stream>>>(k, Ak);
  cvt_f32_bf16<<<8192, 256, 0, stream>>>(v, Av);
  // 2) weight packs
  pack_head_w<<<4096, 256, 0, stream>>>(wq, Bq);
  pack_head_w<<<4096, 256, 0, stream>>>(wk, Bk);
  pack_head_w<<<4096, 256, 0, stream>>>(wv, Bv);
  pack_wo<<<4096, 256, 0, stream>>>(wo, Bo);
  // 3) projections
  gemm_bt<0><<<dim3(64, 8), 256, 0, stream>>>(Aq, Bq, bq, qhb);
  gemm_bt<0><<<dim3(64, 8), 256, 0, stream>>>(Ak, Bk, bk, khb);
  gemm_bt<1><<<dim3(8, 64), 256, 0, stream>>>(Bv, Av, bv, vTb);
  // 4) fused causal attention -> concat bf16 [8192,1024]
  attn_fused<<<dim3(8, 64), 512, 0, stream>>>(qhb, khb, vTb, concat, use_mask);
  // 5) output projection -> fp32 out
  gemm_bt<2><<<dim3(64, 8), 256, 0, stream>>>(concat, Bo, bo, d_out);
}

// Round 3
// 216.073 us; speedup vs baseline: 1.6136x; 1.1026x over previous
//
#include <hip/hip_runtime.h>

// Problem constants
#define B_ 4
#define S_ 2048
#define H_ 16
#define D_ 64
#define E_ 1024
#define M_ 8192   // B_*S_

typedef __attribute__((ext_vector_type(8))) __bf16 bf16x8;
typedef __attribute__((ext_vector_type(4))) __bf16 bf16x4;
typedef __attribute__((ext_vector_type(4))) float f32x4;
typedef __attribute__((ext_vector_type(16))) float f32x16;

// async global->LDS, 16B per lane; LDS base must be wave-uniform
__device__ __forceinline__ void gload_lds16(const void* g, void* l) {
  __builtin_amdgcn_global_load_lds(
      (const __attribute__((address_space(1))) unsigned int*)g,
      (__attribute__((address_space(3))) unsigned int*)l, 16, 0, 0);
}

__device__ __forceinline__ unsigned pk2(float a, float b) {
  union { __bf16 h; unsigned short u; } ua, ub;
  ua.h = (__bf16)a; ub.h = (__bf16)b;
  return ((unsigned)ub.u << 16) | (unsigned)ua.u;
}

// ---------------- fp32 -> bf16 convert (vectorized, G13) ----------------
__global__ void cvt_f32_bf16(const float* __restrict__ in, __bf16* __restrict__ out) {
  const int i = blockIdx.x * blockDim.x + threadIdx.x;  // exactly n/4 threads
  const float4 v = ((const float4*)in)[i];
  bf16x4 o;
  o.x = (__bf16)v.x; o.y = (__bf16)v.y; o.z = (__bf16)v.z; o.w = (__bf16)v.w;
  ((bf16x4*)out)[i] = o;
}

// ---------------- weight packing into B^T layout [n][k] bf16 ----------------
__global__ void pack_head_w(const float* __restrict__ w, __bf16* __restrict__ out) {
  const int idx = blockIdx.x * 256 + threadIdx.x;  // 1024*1024 total
  const int n = idx >> 10, k = idx & 1023;
  out[idx] = (__bf16)w[((size_t)(n >> 6) << 16) + (k << 6) + (n & 63)];
}
__global__ void pack_wo(const float* __restrict__ w, __bf16* __restrict__ out) {
  const int idx = blockIdx.x * 256 + threadIdx.x;
  const int n = idx >> 10, k = idx & 1023;
  out[idx] = (__bf16)w[((size_t)k << 10) + n];
}

// ---------------- bf16 MFMA GEMM: C[M,N] = A[M,K] * Bt[N,K]^T + bias -------
template <int MODE>
__global__ __launch_bounds__(256) void gemm_bt(const __bf16* __restrict__ A,
                                               const __bf16* __restrict__ Bt,
                                               const float* __restrict__ bias,
                                               void* __restrict__ Cout) {
  constexpr int K = 1024;
  __shared__ __bf16 As[128 * 64];
  __shared__ __bf16 Bs[128 * 64];
  const int t = threadIdx.x;
  const int w = t >> 6, l = t & 63;
  const int m0 = blockIdx.x * 128, n0 = blockIdx.y * 128;
  f32x4 acc[4][4] = {};

  for (int kt = 0; kt < K / 64; ++kt) {
    const int kb = kt * 64;
#pragma unroll
    for (int j = 0; j < 4; ++j) {
      const int ci = (j * 4 + w) * 64 + l;
      const int row = ci >> 3;
      const int c = (ci & 7) ^ (row & 7);
      gload_lds16(A + (size_t)(m0 + row) * K + kb + c * 8, As + (j * 4 + w) * 512);
      gload_lds16(Bt + (size_t)(n0 + row) * K + kb + c * 8, Bs + (j * 4 + w) * 512);
    }
    __syncthreads();
#pragma unroll
    for (int kk = 0; kk < 64; kk += 32) {
      bf16x8 af[4], bfr[4];
#pragma unroll
      for (int f = 0; f < 4; ++f) {
        const int ra = (w >> 1) * 64 + f * 16 + (l & 15);
        const int ca = ((kk >> 3) + (l >> 4)) ^ (ra & 7);
        af[f] = *(const bf16x8*)(As + ra * 64 + ca * 8);
        const int rb = (w & 1) * 64 + f * 16 + (l & 15);
        const int cb = ((kk >> 3) + (l >> 4)) ^ (rb & 7);
        bfr[f] = *(const bf16x8*)(Bs + rb * 64 + cb * 8);
      }
#pragma unroll
      for (int mf = 0; mf < 4; ++mf)
#pragma unroll
        for (int nf = 0; nf < 4; ++nf)
          acc[mf][nf] = __builtin_amdgcn_mfma_f32_16x16x32_bf16(af[mf], bfr[nf],
                                                                acc[mf][nf], 0, 0, 0);
    }
    __syncthreads();
  }

#pragma unroll
  for (int mf = 0; mf < 4; ++mf) {
#pragma unroll
    for (int nf = 0; nf < 4; ++nf) {
#pragma unroll
      for (int r = 0; r < 4; ++r) {
        const int gm = m0 + (w >> 1) * 64 + mf * 16 + (l >> 4) * 4 + r;
        const int gn = n0 + (w & 1) * 64 + nf * 16 + (l & 15);
        const float val = acc[mf][nf][r] + ((MODE == 1) ? bias[gm] : bias[gn]);
        if constexpr (MODE == 0) {
          ((__bf16*)Cout)[(((size_t)(gm >> 11) * H_ + (gn >> 6)) * S_ + (gm & 2047)) * D_ + (gn & 63)] =
              (__bf16)val;
        } else if constexpr (MODE == 1) {
          ((__bf16*)Cout)[(((size_t)(gn >> 11) * H_ + (gm >> 6)) * D_ + (gm & 63)) * S_ + (gn & 2047)] =
              (__bf16)val;
        } else {
          ((float*)Cout)[(size_t)gm * 1024 + gn] = val;
        }
      }
    }
  }
}

// ---------------- fused causal flash attention (v3: swapped 32x32, T12) ----
// grid (64 bh, 4 pairs); 512 threads = 8 waves; wave w owns 32 q-rows
// qt*256 + w*32 + (l&31). KV tile 64, double-buffered LDS. Both matmuls
// operand-swapped so softmax state is lane-local (q = lane&31 throughout):
//   S^T = mfma(Kfrag, Qfrag)  -> lane holds 32 of 64 k-scores of its q-row
//   O^T = mfma(VTfrag, PTfrag) -> lane holds 32 of 64 e-values of its q-row
// P redistribution in-register via pack + v_permlane32_swap_b32.
__global__ __launch_bounds__(512, 2) void attn_fused(const __bf16* __restrict__ qh,
                                                     const __bf16* __restrict__ kh,
                                                     const __bf16* __restrict__ vT,
                                                     __bf16* __restrict__ concat,
                                                     const int* __restrict__ use_mask_p) {
  __shared__ __bf16 Ks[2][64 * 64];
  __shared__ __bf16 Vs[2][64 * 64];
  const int t = threadIdx.x, w = t >> 6, l = t & 63;
  const int lo = l & 31, hi = l >> 5;
  const int bh = blockIdx.x, pair = blockIdx.y;
  const int usemask = *use_mask_p;
  const __bf16* Qb = qh + (size_t)bh * S_ * D_;
  const __bf16* Kb = kh + (size_t)bh * S_ * D_;
  const __bf16* Vb = vT + (size_t)bh * D_ * S_;
  const int b = bh >> 4, hh = bh & 15;
  constexpr float CEXP = 0.125f * 1.4426950408889634f;  // scale*log2(e)

  // staging geometry: 512 threads x 16B -> one 64x64 bf16 tile per instr
  const int srow = t >> 3;
  const int sc = (t & 7) ^ (srow & 7);  // inverse-swizzled source chunk

  int cur = 0;
  for (int half = 0; half < 2; ++half) {
    const int qt = half ? (7 - pair) : pair;
    const int qrow0 = qt * 256 + w * 32;
    const int nkt = usemask ? (4 * qt + 4) : (S_ / 64);
    const int ktw = usemask ? (4 * qt + (w >> 1)) : 100000;  // compute if kt<=ktw
    const int ktdiag = usemask ? (4 * qt + (w >> 1)) : -1;

    // Q B-frags (col=lo, k=e contiguous 8 at hi*8), loop-invariant
    bf16x8 qf[4];
#pragma unroll
    for (int ks = 0; ks < 4; ++ks)
      qf[ks] = *(const bf16x8*)(Qb + (size_t)(qrow0 + lo) * D_ + ks * 16 + hi * 8);

    float m = -3e38f, ls = 0.f;
    f32x16 o0 = {}, o1 = {};

    // prologue: stage tile 0 into buf[cur]
    gload_lds16(Kb + (size_t)(0 + srow) * D_ + sc * 8, &Ks[cur][w * 512]);
    gload_lds16(Vb + (size_t)srow * S_ + 0 + sc * 8, &Vs[cur][w * 512]);

    for (int kt = 0; kt < nkt; ++kt) {
      __builtin_amdgcn_sched_barrier(0);
      asm volatile("s_waitcnt vmcnt(0)" ::: "memory");
      __builtin_amdgcn_s_barrier();
      __builtin_amdgcn_sched_barrier(0);

      // stage next tile into the other buffer (overlaps this compute)
      if (kt + 1 < nkt) {
        const int nxt = cur ^ 1;
        gload_lds16(Kb + (size_t)((kt + 1) * 64 + srow) * D_ + sc * 8, &Ks[nxt][w * 512]);
        gload_lds16(Vb + (size_t)srow * S_ + (kt + 1) * 64 + sc * 8, &Vs[nxt][w * 512]);
      }

      if (kt <= ktw) {
        // ---- S^T = K * Q^T ----
        f32x16 s0 = {}, s1 = {};
        __builtin_amdgcn_s_setprio(1);
#pragma unroll
        for (int ks = 0; ks < 4; ++ks) {
          const int ch = ((ks << 1) | hi) ^ (lo & 7);
          const bf16x8 k0 = *(const bf16x8*)(&Ks[cur][lo * 64 + ch * 8]);
          const bf16x8 k1 = *(const bf16x8*)(&Ks[cur][(32 + lo) * 64 + ch * 8]);
          s0 = __builtin_amdgcn_mfma_f32_32x32x16_bf16(k0, qf[ks], s0, 0, 0, 0);
          s1 = __builtin_amdgcn_mfma_f32_32x32x16_bf16(k1, qf[ks], s1, 0, 0, 0);
        }
        __builtin_amdgcn_s_setprio(0);

        if (kt == ktdiag) {  // triangular mask on diagonal tile (raw scores)
          const int qloc = ((w & 1) << 5) + lo;
#pragma unroll
          for (int r = 0; r < 16; ++r) {
            const int kv0 = (r & 3) + 8 * (r >> 2) + 4 * hi;
            if (kv0 > qloc) s0[r] = -1e30f;
            if (kv0 + 32 > qloc) s1[r] = -1e30f;
          }
        }

        // ---- online softmax, lane-local (q = lo; partner = l^32) ----
        float pm = s0[0];
#pragma unroll
        for (int r = 1; r < 16; ++r) pm = fmaxf(pm, s0[r]);
#pragma unroll
        for (int r = 0; r < 16; ++r) pm = fmaxf(pm, s1[r]);
        pm = fmaxf(pm, __shfl_xor(pm, 32));

        // defer-max: 64 raw units == 8 logit units (scale 0.125)
        if (!__all(pm - m <= 64.0f)) {
          const float mn = fmaxf(m, pm);
          const float al = __builtin_amdgcn_exp2f((m - mn) * CEXP);
          m = mn;
          ls *= al;
          o0 *= al;
          o1 *= al;
        }

        // exp + pack into 4-value blocks (2 words each): W[mf][j]
        unsigned W0[4][2], W1[4][2];
        float rs0 = 0.f, rs1 = 0.f;
#pragma unroll
        for (int j = 0; j < 4; ++j) {
          float p0 = __builtin_amdgcn_exp2f((s0[4 * j + 0] - m) * CEXP);
          float p1 = __builtin_amdgcn_exp2f((s0[4 * j + 1] - m) * CEXP);
          float p2 = __builtin_amdgcn_exp2f((s0[4 * j + 2] - m) * CEXP);
          float p3 = __builtin_amdgcn_exp2f((s0[4 * j + 3] - m) * CEXP);
          rs0 += (p0 + p1) + (p2 + p3);
          W0[j][0] = pk2(p0, p1);
          W0[j][1] = pk2(p2, p3);
          float q0 = __builtin_amdgcn_exp2f((s1[4 * j + 0] - m) * CEXP);
          float q1 = __builtin_amdgcn_exp2f((s1[4 * j + 1] - m) * CEXP);
          float q2 = __builtin_amdgcn_exp2f((s1[4 * j + 2] - m) * CEXP);
          float q3 = __builtin_amdgcn_exp2f((s1[4 * j + 3] - m) * CEXP);
          rs1 += (q0 + q1) + (q2 + q3);
          W1[j][0] = pk2(q0, q1);
          W1[j][1] = pk2(q2, q3);
        }
        float rs = rs0 + rs1;
        rs += __shfl_xor(rs, 32);
        ls += rs;

        // build P^T B-frags in-register: one permlane32_swap per word pair
        bf16x8 pa[4];
#pragma unroll
        for (int ks = 0; ks < 4; ++ks) {
          const int c = ks & 1;
          unsigned x0, x1, y0, y1;
          if ((ks >> 1) == 0) {
            x0 = W0[2 * c][0]; x1 = W0[2 * c][1];
            y0 = W0[2 * c + 1][0]; y1 = W0[2 * c + 1][1];
          } else {
            x0 = W1[2 * c][0]; x1 = W1[2 * c][1];
            y0 = W1[2 * c + 1][0]; y1 = W1[2 * c + 1][1];
          }
          asm volatile("v_permlane32_swap_b32 %0, %1" : "+v"(x0), "+v"(y0));
          asm volatile("v_permlane32_swap_b32 %0, %1" : "+v"(x1), "+v"(y1));
          union { unsigned u[4]; bf16x8 v; } uu;
          uu.u[0] = x0; uu.u[1] = x1; uu.u[2] = y0; uu.u[3] = y1;
          pa[ks] = uu.v;
        }

        // ---- O^T += V^T * P^T ----
        __builtin_amdgcn_s_setprio(1);
#pragma unroll
        for (int ks = 0; ks < 4; ++ks) {
          const int ch = ((ks << 1) | hi) ^ (lo & 7);
          const bf16x8 v0 = *(const bf16x8*)(&Vs[cur][lo * 64 + ch * 8]);
          const bf16x8 v1 = *(const bf16x8*)(&Vs[cur][(32 + lo) * 64 + ch * 8]);
          o0 = __builtin_amdgcn_mfma_f32_32x32x16_bf16(v0, pa[ks], o0, 0, 0, 0);
          o1 = __builtin_amdgcn_mfma_f32_32x32x16_bf16(v1, pa[ks], o1, 0, 0, 0);
        }
        __builtin_amdgcn_s_setprio(0);
      }
      cur ^= 1;
    }

    // epilogue: out[qrow][h*64 + e] = o^T[e][q]/ls ; e = mf*32+(r&3)+8*(r>>2)+4*hi
    const float inv = 1.0f / ls;
    const size_t rowbase = ((size_t)(b * S_ + qrow0 + lo)) * E_ + hh * 64;
#pragma unroll
    for (int rr = 0; rr < 4; ++rr) {
      bf16x4 v0, v1;
#pragma unroll
      for (int bb = 0; bb < 4; ++bb) {
        v0[bb] = (__bf16)(o0[4 * rr + bb] * inv);
        v1[bb] = (__bf16)(o1[4 * rr + bb] * inv);
      }
      *(bf16x4*)(concat + rowbase + 8 * rr + 4 * hi) = v0;
      *(bf16x4*)(concat + rowbase + 32 + 8 * rr + 4 * hi) = v1;
    }
  }
}

// ---------------- launch ----------------
extern "C" void kernel_launch(void* const* d_in, const int* in_sizes, int n_in,
                              void* d_out, int out_size, void* d_ws, size_t ws_size,
                              hipStream_t stream) {
  const float* q = (const float*)d_in[0];
  const float* k = (const float*)d_in[1];
  const float* v = (const float*)d_in[2];
  const float* wq = (const float*)d_in[3];
  const float* bq = (const float*)d_in[4];
  const float* wk = (const float*)d_in[5];
  const float* bk = (const float*)d_in[6];
  const float* wv = (const float*)d_in[7];
  const float* bv = (const float*)d_in[8];
  const float* wo = (const float*)d_in[9];
  const float* bo = (const float*)d_in[10];
  const int* use_mask = (const int*)d_in[11];
  (void)in_sizes; (void)n_in; (void)out_size; (void)ws_size;

  char* ws = (char*)d_ws;
  __bf16* Aq = (__bf16*)ws;                       // [8192,1024] bf16
  __bf16* Ak = Aq + (size_t)M_ * E_;
  __bf16* Av = Ak + (size_t)M_ * E_;
  __bf16* Bq = Av + (size_t)M_ * E_;              // packed weights [1024,1024]
  __bf16* Bk = Bq + (size_t)E_ * E_;
  __bf16* Bv = Bk + (size_t)E_ * E_;
  __bf16* Bo = Bv + (size_t)E_ * E_;
  __bf16* qhb = Bo + (size_t)E_ * E_;             // [B,H,S,64]
  __bf16* khb = qhb + (size_t)8388608;
  __bf16* vTb = khb + (size_t)8388608;            // [B,H,64,S]
  __bf16* concat = Aq;  // reuse Aq region after projections are consumed

  // 1) converts
  cvt_f32_bf16<<<8192, 256, 0, stream>>>(q, Aq);
  cvt_f32_bf16<<<8192, 256, 0, stream>>>(k, Ak);
  cvt_f32_bf16<<<8192, 256, 0, stream>>>(v, Av);
  // 2) weight packs
  pack_head_w<<<4096, 256, 0, stream>>>(wq, Bq);
  pack_head_w<<<4096, 256, 0, stream>>>(wk, Bk);
  pack_head_w<<<4096, 256, 0, stream>>>(wv, Bv);
  pack_wo<<<4096, 256, 0, stream>>>(wo, Bo);
  // 3) projections
  gemm_bt<0><<<dim3(64, 8), 256, 0, stream>>>(Aq, Bq, bq, qhb);
  gemm_bt<0><<<dim3(64, 8), 256, 0, stream>>>(Ak, Bk, bk, khb);
  gemm_bt<1><<<dim3(8, 64), 256, 0, stream>>>(Bv, Av, bv, vTb);
  // 4) fused causal attention -> concat bf16 [8192,1024]
  attn_fused<<<dim3(64, 4), 512, 0, stream>>>(qhb, khb, vTb, concat, use_mask);
  // 5) output projection -> fp32 out
  gemm_bt<2><<<dim3(64, 8), 256, 0, stream>>>(concat, Bo, bo, d_out);
}

// Round 6
// 206.962 us; speedup vs baseline: 1.6847x; 1.0440x over previous
//
#include <hip/hip_runtime.h>

// Problem constants
#define B_ 4
#define S_ 2048
#define H_ 16
#define D_ 64
#define E_ 1024
#define M_ 8192   // B_*S_

typedef __attribute__((ext_vector_type(8))) __bf16 bf16x8;
typedef __attribute__((ext_vector_type(4))) __bf16 bf16x4;
typedef __attribute__((ext_vector_type(4))) float f32x4;
typedef __attribute__((ext_vector_type(16))) float f32x16;

// async global->LDS, 16B per lane; LDS base must be wave-uniform
__device__ __forceinline__ void gload_lds16(const void* g, void* l) {
  __builtin_amdgcn_global_load_lds(
      (const __attribute__((address_space(1))) unsigned int*)g,
      (__attribute__((address_space(3))) unsigned int*)l, 16, 0, 0);
}

__device__ __forceinline__ unsigned pk2(float a, float b) {
  union { __bf16 h; unsigned short u; } ua, ub;
  ua.h = (__bf16)a; ub.h = (__bf16)b;
  return ((unsigned)ub.u << 16) | (unsigned)ua.u;
}

// ---------------- fp32 -> bf16 convert, 3 tensors in one dispatch ----------
// (exonerated by round-4/5 forensics: ran correctly; 2-D grid)
__global__ void cvt_all(const float* __restrict__ q, const float* __restrict__ k,
                        const float* __restrict__ v, __bf16* __restrict__ Aq,
                        __bf16* __restrict__ Ak, __bf16* __restrict__ Av) {
  const int y = blockIdx.y;
  const float* src = (y == 0) ? q : (y == 1) ? k : v;
  __bf16* dst = (y == 0) ? Aq : (y == 1) ? Ak : Av;
  const int i = blockIdx.x * blockDim.x + threadIdx.x;
  const float4 vv = ((const float4*)src)[i];
  bf16x4 o;
  o.x = (__bf16)vv.x; o.y = (__bf16)vv.y; o.z = (__bf16)vv.z; o.w = (__bf16)vv.w;
  ((bf16x4*)dst)[i] = o;
}

// ---------------- weight packing into B^T layout [n][k] bf16, one dispatch --
// (exonerated: Bo provably correct in round-4/5 failures; 2-D grid)
__global__ void pack_all(const float* __restrict__ wq, const float* __restrict__ wk,
                         const float* __restrict__ wv, const float* __restrict__ wo,
                         __bf16* __restrict__ Bq, __bf16* __restrict__ Bk,
                         __bf16* __restrict__ Bv, __bf16* __restrict__ Bo) {
  const int y = blockIdx.y;
  const int idx = blockIdx.x * 256 + threadIdx.x;  // 1024*1024 total
  const int n = idx >> 10, kk = idx & 1023;
  if (y < 3) {
    const float* w = (y == 0) ? wq : (y == 1) ? wk : wv;
    __bf16* out = (y == 0) ? Bq : (y == 1) ? Bk : Bv;
    out[idx] = (__bf16)w[((size_t)(n >> 6) << 16) + (kk << 6) + (n & 63)];
  } else {
    Bo[idx] = (__bf16)wo[((size_t)kk << 10) + n];
  }
}

// ---------------- bf16 MFMA GEMM: C[M,N] = A[M,K] * Bt[N,K]^T + bias -------
// Round-3 verbatim. 128x128 tile, BK=64, 256 threads (4 waves, 2x2),
// global_load_lds w16, XOR chunk-swizzle (rule 21).
// MODE 0: scatter bf16 to [B,H,S,D], bias[gn]
// MODE 1: scatter bf16 to [B,H,D,S] (A is weights, Bt is activations), bias[gm]
// MODE 2: fp32 C[gm*1024+gn] = acc + bias[gn]
template <int MODE>
__global__ __launch_bounds__(256) void gemm_bt(const __bf16* __restrict__ A,
                                               const __bf16* __restrict__ Bt,
                                               const float* __restrict__ bias,
                                               void* __restrict__ Cout) {
  constexpr int K = 1024;
  __shared__ __bf16 As[128 * 64];
  __shared__ __bf16 Bs[128 * 64];
  const int t = threadIdx.x;
  const int w = t >> 6, l = t & 63;
  const int m0 = blockIdx.x * 128, n0 = blockIdx.y * 128;
  f32x4 acc[4][4] = {};

  for (int kt = 0; kt < K / 64; ++kt) {
    const int kb = kt * 64;
#pragma unroll
    for (int j = 0; j < 4; ++j) {
      const int ci = (j * 4 + w) * 64 + l;
      const int row = ci >> 3;
      const int c = (ci & 7) ^ (row & 7);
      gload_lds16(A + (size_t)(m0 + row) * K + kb + c * 8, As + (j * 4 + w) * 512);
      gload_lds16(Bt + (size_t)(n0 + row) * K + kb + c * 8, Bs + (j * 4 + w) * 512);
    }
    __syncthreads();
#pragma unroll
    for (int kk = 0; kk < 64; kk += 32) {
      bf16x8 af[4], bfr[4];
#pragma unroll
      for (int f = 0; f < 4; ++f) {
        const int ra = (w >> 1) * 64 + f * 16 + (l & 15);
        const int ca = ((kk >> 3) + (l >> 4)) ^ (ra & 7);
        af[f] = *(const bf16x8*)(As + ra * 64 + ca * 8);
        const int rb = (w & 1) * 64 + f * 16 + (l & 15);
        const int cb = ((kk >> 3) + (l >> 4)) ^ (rb & 7);
        bfr[f] = *(const bf16x8*)(Bs + rb * 64 + cb * 8);
      }
#pragma unroll
      for (int mf = 0; mf < 4; ++mf)
#pragma unroll
        for (int nf = 0; nf < 4; ++nf)
          acc[mf][nf] = __builtin_amdgcn_mfma_f32_16x16x32_bf16(af[mf], bfr[nf],
                                                                acc[mf][nf], 0, 0, 0);
    }
    __syncthreads();
  }

#pragma unroll
  for (int mf = 0; mf < 4; ++mf) {
#pragma unroll
    for (int nf = 0; nf < 4; ++nf) {
#pragma unroll
      for (int r = 0; r < 4; ++r) {
        const int gm = m0 + (w >> 1) * 64 + mf * 16 + (l >> 4) * 4 + r;
        const int gn = n0 + (w & 1) * 64 + nf * 16 + (l & 15);
        const float val = acc[mf][nf][r] + ((MODE == 1) ? bias[gm] : bias[gn]);
        if constexpr (MODE == 0) {
          ((__bf16*)Cout)[(((size_t)(gm >> 11) * H_ + (gn >> 6)) * S_ + (gm & 2047)) * D_ + (gn & 63)] =
              (__bf16)val;
        } else if constexpr (MODE == 1) {
          ((__bf16*)Cout)[(((size_t)(gn >> 11) * H_ + (gm >> 6)) * D_ + (gm & 63)) * S_ + (gn & 2047)] =
              (__bf16)val;
        } else {
          ((float*)Cout)[(size_t)gm * 1024 + gn] = val;
        }
      }
    }
  }
}

// ---------------- fused causal flash attention (v3: round-3 verbatim) ------
// grid (64 bh, 4 pairs); 512 threads = 8 waves; wave w owns 32 q-rows
// qt*256 + w*32 + (l&31). KV tile 64, double-buffered LDS. Both matmuls
// operand-swapped so softmax state is lane-local (q = lane&31 throughout).
__global__ __launch_bounds__(512, 2) void attn_fused(const __bf16* __restrict__ qh,
                                                     const __bf16* __restrict__ kh,
                                                     const __bf16* __restrict__ vT,
                                                     __bf16* __restrict__ concat,
                                                     const int* __restrict__ use_mask_p) {
  __shared__ __bf16 Ks[2][64 * 64];
  __shared__ __bf16 Vs[2][64 * 64];
  const int t = threadIdx.x, w = t >> 6, l = t & 63;
  const int lo = l & 31, hi = l >> 5;
  const int bh = blockIdx.x, pair = blockIdx.y;
  const int usemask = *use_mask_p;
  const __bf16* Qb = qh + (size_t)bh * S_ * D_;
  const __bf16* Kb = kh + (size_t)bh * S_ * D_;
  const __bf16* Vb = vT + (size_t)bh * D_ * S_;
  const int b = bh >> 4, hh = bh & 15;
  constexpr float CEXP = 0.125f * 1.4426950408889634f;  // scale*log2(e)

  // staging geometry: 512 threads x 16B -> one 64x64 bf16 tile per instr
  const int srow = t >> 3;
  const int sc = (t & 7) ^ (srow & 7);  // inverse-swizzled source chunk

  int cur = 0;
  for (int half = 0; half < 2; ++half) {
    const int qt = half ? (7 - pair) : pair;
    const int qrow0 = qt * 256 + w * 32;
    const int nkt = usemask ? (4 * qt + 4) : (S_ / 64);
    const int ktw = usemask ? (4 * qt + (w >> 1)) : 100000;  // compute if kt<=ktw
    const int ktdiag = usemask ? (4 * qt + (w >> 1)) : -1;

    // Q B-frags (col=lo, k=e contiguous 8 at hi*8), loop-invariant
    bf16x8 qf[4];
#pragma unroll
    for (int ks = 0; ks < 4; ++ks)
      qf[ks] = *(const bf16x8*)(Qb + (size_t)(qrow0 + lo) * D_ + ks * 16 + hi * 8);

    float m = -3e38f, ls = 0.f;
    f32x16 o0 = {}, o1 = {};

    // prologue: stage tile 0 into buf[cur]
    gload_lds16(Kb + (size_t)(0 + srow) * D_ + sc * 8, &Ks[cur][w * 512]);
    gload_lds16(Vb + (size_t)srow * S_ + 0 + sc * 8, &Vs[cur][w * 512]);

    for (int kt = 0; kt < nkt; ++kt) {
      __builtin_amdgcn_sched_barrier(0);
      asm volatile("s_waitcnt vmcnt(0)" ::: "memory");
      __builtin_amdgcn_s_barrier();
      __builtin_amdgcn_sched_barrier(0);

      // stage next tile into the other buffer (overlaps this compute)
      if (kt + 1 < nkt) {
        const int nxt = cur ^ 1;
        gload_lds16(Kb + (size_t)((kt + 1) * 64 + srow) * D_ + sc * 8, &Ks[nxt][w * 512]);
        gload_lds16(Vb + (size_t)srow * S_ + (kt + 1) * 64 + sc * 8, &Vs[nxt][w * 512]);
      }

      if (kt <= ktw) {
        // ---- S^T = K * Q^T ----
        f32x16 s0 = {}, s1 = {};
        __builtin_amdgcn_s_setprio(1);
#pragma unroll
        for (int ks = 0; ks < 4; ++ks) {
          const int ch = ((ks << 1) | hi) ^ (lo & 7);
          const bf16x8 k0 = *(const bf16x8*)(&Ks[cur][lo * 64 + ch * 8]);
          const bf16x8 k1 = *(const bf16x8*)(&Ks[cur][(32 + lo) * 64 + ch * 8]);
          s0 = __builtin_amdgcn_mfma_f32_32x32x16_bf16(k0, qf[ks], s0, 0, 0, 0);
          s1 = __builtin_amdgcn_mfma_f32_32x32x16_bf16(k1, qf[ks], s1, 0, 0, 0);
        }
        __builtin_amdgcn_s_setprio(0);

        if (kt == ktdiag) {  // triangular mask on diagonal tile (raw scores)
          const int qloc = ((w & 1) << 5) + lo;
#pragma unroll
          for (int r = 0; r < 16; ++r) {
            const int kv0 = (r & 3) + 8 * (r >> 2) + 4 * hi;
            if (kv0 > qloc) s0[r] = -1e30f;
            if (kv0 + 32 > qloc) s1[r] = -1e30f;
          }
        }

        // ---- online softmax, lane-local (q = lo; partner = l^32) ----
        float pm = s0[0];
#pragma unroll
        for (int r = 1; r < 16; ++r) pm = fmaxf(pm, s0[r]);
#pragma unroll
        for (int r = 0; r < 16; ++r) pm = fmaxf(pm, s1[r]);
        pm = fmaxf(pm, __shfl_xor(pm, 32));

        // defer-max: 64 raw units == 8 logit units (scale 0.125)
        if (!__all(pm - m <= 64.0f)) {
          const float mn = fmaxf(m, pm);
          const float al = __builtin_amdgcn_exp2f((m - mn) * CEXP);
          m = mn;
          ls *= al;
          o0 *= al;
          o1 *= al;
        }

        // exp + pack into 4-value blocks (2 words each): W[mf][j]
        unsigned W0[4][2], W1[4][2];
        float rs0 = 0.f, rs1 = 0.f;
#pragma unroll
        for (int j = 0; j < 4; ++j) {
          float p0 = __builtin_amdgcn_exp2f((s0[4 * j + 0] - m) * CEXP);
          float p1 = __builtin_amdgcn_exp2f((s0[4 * j + 1] - m) * CEXP);
          float p2 = __builtin_amdgcn_exp2f((s0[4 * j + 2] - m) * CEXP);
          float p3 = __builtin_amdgcn_exp2f((s0[4 * j + 3] - m) * CEXP);
          rs0 += (p0 + p1) + (p2 + p3);
          W0[j][0] = pk2(p0, p1);
          W0[j][1] = pk2(p2, p3);
          float q0 = __builtin_amdgcn_exp2f((s1[4 * j + 0] - m) * CEXP);
          float q1 = __builtin_amdgcn_exp2f((s1[4 * j + 1] - m) * CEXP);
          float q2 = __builtin_amdgcn_exp2f((s1[4 * j + 2] - m) * CEXP);
          float q3 = __builtin_amdgcn_exp2f((s1[4 * j + 3] - m) * CEXP);
          rs1 += (q0 + q1) + (q2 + q3);
          W1[j][0] = pk2(q0, q1);
          W1[j][1] = pk2(q2, q3);
        }
        float rs = rs0 + rs1;
        rs += __shfl_xor(rs, 32);
        ls += rs;

        // build P^T B-frags in-register: one permlane32_swap per word pair
        bf16x8 pa[4];
#pragma unroll
        for (int ks = 0; ks < 4; ++ks) {
          const int c = ks & 1;
          unsigned x0, x1, y0, y1;
          if ((ks >> 1) == 0) {
            x0 = W0[2 * c][0]; x1 = W0[2 * c][1];
            y0 = W0[2 * c + 1][0]; y1 = W0[2 * c + 1][1];
          } else {
            x0 = W1[2 * c][0]; x1 = W1[2 * c][1];
            y0 = W1[2 * c + 1][0]; y1 = W1[2 * c + 1][1];
          }
          asm volatile("v_permlane32_swap_b32 %0, %1" : "+v"(x0), "+v"(y0));
          asm volatile("v_permlane32_swap_b32 %0, %1" : "+v"(x1), "+v"(y1));
          union { unsigned u[4]; bf16x8 v; } uu;
          uu.u[0] = x0; uu.u[1] = x1; uu.u[2] = y0; uu.u[3] = y1;
          pa[ks] = uu.v;
        }

        // ---- O^T += V^T * P^T ----
        __builtin_amdgcn_s_setprio(1);
#pragma unroll
        for (int ks = 0; ks < 4; ++ks) {
          const int ch = ((ks << 1) | hi) ^ (lo & 7);
          const bf16x8 v0 = *(const bf16x8*)(&Vs[cur][lo * 64 + ch * 8]);
          const bf16x8 v1 = *(const bf16x8*)(&Vs[cur][(32 + lo) * 64 + ch * 8]);
          o0 = __builtin_amdgcn_mfma_f32_32x32x16_bf16(v0, pa[ks], o0, 0, 0, 0);
          o1 = __builtin_amdgcn_mfma_f32_32x32x16_bf16(v1, pa[ks], o1, 0, 0, 0);
        }
        __builtin_amdgcn_s_setprio(0);
      }
      cur ^= 1;
    }

    // epilogue: out[qrow][h*64 + e] = o^T[e][q]/ls ; e = mf*32+(r&3)+8*(r>>2)+4*hi
    const float inv = 1.0f / ls;
    const size_t rowbase = ((size_t)(b * S_ + qrow0 + lo)) * E_ + hh * 64;
#pragma unroll
    for (int rr = 0; rr < 4; ++rr) {
      bf16x4 v0, v1;
#pragma unroll
      for (int bb = 0; bb < 4; ++bb) {
        v0[bb] = (__bf16)(o0[4 * rr + bb] * inv);
        v1[bb] = (__bf16)(o1[4 * rr + bb] * inv);
      }
      *(bf16x4*)(concat + rowbase + 8 * rr + 4 * hi) = v0;
      *(bf16x4*)(concat + rowbase + 32 + 8 * rr + 4 * hi) = v1;
    }
  }
}

// ---------------- launch ----------------
extern "C" void kernel_launch(void* const* d_in, const int* in_sizes, int n_in,
                              void* d_out, int out_size, void* d_ws, size_t ws_size,
                              hipStream_t stream) {
  const float* q = (const float*)d_in[0];
  const float* k = (const float*)d_in[1];
  const float* v = (const float*)d_in[2];
  const float* wq = (const float*)d_in[3];
  const float* bq = (const float*)d_in[4];
  const float* wk = (const float*)d_in[5];
  const float* bk = (const float*)d_in[6];
  const float* wv = (const float*)d_in[7];
  const float* bv = (const float*)d_in[8];
  const float* wo = (const float*)d_in[9];
  const float* bo = (const float*)d_in[10];
  const int* use_mask = (const int*)d_in[11];
  (void)in_sizes; (void)n_in; (void)out_size; (void)ws_size;

  char* ws = (char*)d_ws;
  __bf16* Aq = (__bf16*)ws;                       // [8192,1024] bf16
  __bf16* Ak = Aq + (size_t)M_ * E_;
  __bf16* Av = Ak + (size_t)M_ * E_;
  __bf16* Bq = Av + (size_t)M_ * E_;              // packed weights [1024,1024]
  __bf16* Bk = Bq + (size_t)E_ * E_;
  __bf16* Bv = Bk + (size_t)E_ * E_;
  __bf16* Bo = Bv + (size_t)E_ * E_;
  __bf16* qhb = Bo + (size_t)E_ * E_;             // [B,H,S,64]
  __bf16* khb = qhb + (size_t)8388608;
  __bf16* vTb = khb + (size_t)8388608;            // [B,H,64,S]
  __bf16* concat = Aq;  // reuse Aq region after projections are consumed

  // NOTE: grid.z > 1 dispatches silently did not execute in this harness
  // (round-4/5 forensics) — keep all grids 1-D/2-D.
  cvt_all<<<dim3(8192, 3), 256, 0, stream>>>(q, k, v, Aq, Ak, Av);
  pack_all<<<dim3(4096, 4), 256, 0, stream>>>(wq, wk, wv, wo, Bq, Bk, Bv, Bo);
  gemm_bt<0><<<dim3(64, 8), 256, 0, stream>>>(Aq, Bq, bq, qhb);
  gemm_bt<0><<<dim3(64, 8), 256, 0, stream>>>(Ak, Bk, bk, khb);
  gemm_bt<1><<<dim3(8, 64), 256, 0, stream>>>(Bv, Av, bv, vTb);
  attn_fused<<<dim3(64, 4), 512, 0, stream>>>(qhb, khb, vTb, concat, use_mask);
  gemm_bt<2><<<dim3(64, 8), 256, 0, stream>>>(concat, Bo, bo, d_out);
}